// Round 1
// baseline (778.053 us; speedup 1.0000x reference)
//
#include <hip/hip_runtime.h>
#include <math.h>

#define N_ROWS 32768
#define D 256
#define C 16

// workspace layout in floats
#define WS_SUMS_A 0
#define WS_SQ_A   4096
#define WS_SUMS_B 8192
#define WS_SQ_B   12288
#define WS_INV    16384
#define WS_COV    16385
#define WS_COUNTS 16392   /* int[16] */
#define WS_CURSOR 16408   /* int[16] */
#define WS_PERM   16640   /* int[32768] */
#define WS_ZERO_FLOATS 16408

__global__ __launch_bounds__(256) void k_hist(const int* __restrict__ labels,
                                              int* __restrict__ counts) {
    __shared__ int h[C];
    const int t = threadIdx.x;
    if (t < C) h[t] = 0;
    __syncthreads();
    const int i = blockIdx.x * 256 + t;
    atomicAdd(&h[labels[i]], 1);
    __syncthreads();
    if (t < C) atomicAdd(&counts[t], h[t]);
}

__global__ void k_scan(const int* __restrict__ counts, int* __restrict__ cursor) {
    if (threadIdx.x == 0) {
        int off = 0;
        for (int c = 0; c < C; ++c) { cursor[c] = off; off += counts[c]; }
    }
}

__global__ __launch_bounds__(256) void k_scatter(const int* __restrict__ labels,
                                                 int* __restrict__ cursor,
                                                 int* __restrict__ perm) {
    __shared__ int lh[C];
    __shared__ int lbase[C];
    const int t = threadIdx.x;
    if (t < C) lh[t] = 0;
    __syncthreads();
    const int i = blockIdx.x * 256 + t;
    const int lab = labels[i];
    const int lr = atomicAdd(&lh[lab], 1);
    __syncthreads();
    if (t < C) lbase[t] = atomicAdd(&cursor[t], lh[t]);
    __syncthreads();
    perm[lbase[lab] + lr] = i;
}

// Per-class sums & sq-sums via LDS accumulation (thread t owns column t),
// plus inv_loss partial on the y==0 pass.
__global__ __launch_bounds__(256) void k_stats(const float* __restrict__ za,
                                               const float* __restrict__ zb,
                                               const int* __restrict__ labels,
                                               float* __restrict__ ws) {
    const int t = threadIdx.x;
    const int inp = blockIdx.y;
    __shared__ float S[2 * C * D];   // 32 KB: [0..4095]=sum, [4096..8191]=sq
    for (int i = t; i < 2 * C * D; i += 256) S[i] = 0.f;
    __syncthreads();
    const float* X = inp ? zb : za;
    float* sums = ws + (inp ? WS_SUMS_B : WS_SUMS_A);
    float* sqs  = ws + (inp ? WS_SQ_B  : WS_SQ_A);
    const int r0 = blockIdx.x * 128;
    float invp = 0.f;
    #pragma unroll 2
    for (int r = r0; r < r0 + 128; ++r) {
        const int lab = labels[r];
        const float v = X[r * D + t];
        S[lab * D + t] += v;
        S[(C + lab) * D + t] += v * v;
        if (inp == 0) {
            const float w2 = zb[r * D + t];
            const float dd = v - w2;
            invp += dd * dd;
        }
    }
    __syncthreads();
    #pragma unroll
    for (int c = 0; c < C; ++c) {
        atomicAdd(&sums[c * D + t], S[c * D + t]);
        atomicAdd(&sqs[c * D + t],  S[(C + c) * D + t]);
    }
    if (inp == 0) {
        for (int o = 32; o > 0; o >>= 1) invp += __shfl_down(invp, o, 64);
        if ((t & 63) == 0) atomicAdd(&ws[WS_INV], invp);
    }
}

// Per (input, class, 64x64 tile): Gram over the class rows (gathered via perm),
// then cov = (G - n m m^T)/(n-1), accumulate off-diagonal cov^2 into ws[WS_COV].
__global__ __launch_bounds__(256) void k_gram(const float* __restrict__ za,
                                              const float* __restrict__ zb,
                                              const int* __restrict__ perm,
                                              const int* __restrict__ counts,
                                              float* __restrict__ ws) {
    const int t = threadIdx.x;
    const int tile = blockIdx.x;          // 0..15
    const int tx = tile & 3, ty = tile >> 2;
    const int cls = blockIdx.y;
    const int inp = blockIdx.z;
    const float* X = inp ? zb : za;
    const float* sums = ws + (inp ? WS_SUMS_B : WS_SUMS_A);

    int offs = 0;
    for (int c = 0; c < cls; ++c) offs += counts[c];
    const int cnt = counts[cls];

    __shared__ __align__(16) float Lm[64][68];
    __shared__ __align__(16) float Ln[64][68];

    float acc[4][4] = {};
    const int sx = t & 15, sy = t >> 4;
    const int cm0 = tx * 64, cn0 = ty * 64;

    const int half  = (t >> 6) & 1;
    const int col   = t & 63;
    const int rbase = t >> 7;             // 0..1
    const int cbase = (half ? cn0 : cm0) + col;

    for (int k0 = 0; k0 < cnt; k0 += 64) {
        __syncthreads();
        #pragma unroll 8
        for (int i = 0; i < 32; ++i) {
            const int row = i * 2 + rbase;
            const int kk = k0 + row;
            float v = 0.f;
            if (kk < cnt) v = X[perm[offs + kk] * D + cbase];
            if (half) Ln[row][col] = v; else Lm[row][col] = v;
        }
        __syncthreads();
        #pragma unroll 4
        for (int k = 0; k < 64; ++k) {
            const float4 av = *(const float4*)(&Lm[k][sx * 4]);
            const float4 bv = *(const float4*)(&Ln[k][sy * 4]);
            const float am[4] = {av.x, av.y, av.z, av.w};
            const float bn[4] = {bv.x, bv.y, bv.z, bv.w};
            #pragma unroll
            for (int i = 0; i < 4; ++i)
                #pragma unroll
                for (int j = 0; j < 4; ++j)
                    acc[i][j] += am[i] * bn[j];
        }
    }

    const float fc = (float)cnt;
    const float cinv = 1.f / fc;
    const float uinv = 1.f / (fc - 1.f);
    float mm[4], mn[4];
    #pragma unroll
    for (int i = 0; i < 4; ++i) mm[i] = sums[cls * D + cm0 + sx * 4 + i] * cinv;
    #pragma unroll
    for (int j = 0; j < 4; ++j) mn[j] = sums[cls * D + cn0 + sy * 4 + j] * cinv;

    float local = 0.f;
    #pragma unroll
    for (int i = 0; i < 4; ++i) {
        #pragma unroll
        for (int j = 0; j < 4; ++j) {
            const int gm = cm0 + sx * 4 + i;
            const int gn = cn0 + sy * 4 + j;
            const float cov = (acc[i][j] - fc * mm[i] * mn[j]) * uinv;
            if (gm != gn) local += cov * cov;
        }
    }
    for (int o = 32; o > 0; o >>= 1) local += __shfl_down(local, o, 64);
    if ((t & 63) == 0) atomicAdd(&ws[WS_COV], local);
}

__global__ __launch_bounds__(256) void k_final(const float* __restrict__ ws,
                                               float* __restrict__ out) {
    __shared__ float M[C * D];    // midpoint means, 16 KB
    __shared__ float redv[4];
    __shared__ float redp[4];
    const int t = threadIdx.x;
    const int* counts = (const int*)ws + WS_COUNTS;

    // variance loss partial over 2*C*D entries
    float vsum = 0.f;
    for (int idx = t; idx < 2 * C * D; idx += 256) {
        const int inp = idx >> 12;
        const int cd = idx & 4095;
        const int c = cd >> 8;
        const float cnt = (float)counts[c];
        const float s  = ws[(inp ? WS_SUMS_B : WS_SUMS_A) + cd];
        const float sq = ws[(inp ? WS_SQ_B   : WS_SQ_A)   + cd];
        const float mean = s / cnt;
        const float var = (sq - cnt * mean * mean) / (cnt - 1.f);
        vsum += fmaxf(1.f - sqrtf(var + 1e-4f), 0.f);
    }
    // midpoint means into LDS
    for (int cd = t; cd < C * D; cd += 256) {
        const int c = cd >> 8;
        const float cnt = (float)counts[c];
        M[cd] = 0.5f * (ws[WS_SUMS_A + cd] + ws[WS_SUMS_B + cd]) / cnt;
    }
    for (int o = 32; o > 0; o >>= 1) vsum += __shfl_down(vsum, o, 64);
    if ((t & 63) == 0) redv[t >> 6] = vsum;
    __syncthreads();

    // class-discriminative pairs: wave w handles pairs with p%4==w
    const int wv = t >> 6, ln = t & 63;
    float psum = 0.f;
    int p = 0;
    for (int i = 0; i < C; ++i) {
        for (int j = i + 1; j < C; ++j, ++p) {
            if ((p & 3) != wv) continue;
            float d2 = 0.f;
            #pragma unroll
            for (int d = ln; d < D; d += 64) {
                const float df = M[i * D + d] - M[j * D + d];
                d2 += df * df;
            }
            for (int o = 32; o > 0; o >>= 1) d2 += __shfl_down(d2, o, 64);
            if (ln == 0) {
                const float dist = sqrtf(d2);
                const float r = fmaxf(50.f - dist, 0.f);
                psum += r * r;
            }
        }
    }
    if (ln == 0) redp[wv] = psum;
    __syncthreads();

    if (t == 0) {
        const float var_total = redv[0] + redv[1] + redv[2] + redv[3];
        const float var_loss = var_total / 8192.f;          // 0.5*(mean_a+mean_b)
        const float class_sum = redp[0] + redp[1] + redp[2] + redp[3];
        const float class_loss = class_sum / 120.f;
        const float inv_loss = ws[WS_INV] / (float)(N_ROWS * D);
        const float cov_loss = 0.5f * ws[WS_COV] / (float)(C * D);
        out[0] = 25.f * inv_loss + 25.f * var_loss + 1.f * cov_loss + 50.f * class_loss;
    }
}

extern "C" void kernel_launch(void* const* d_in, const int* in_sizes, int n_in,
                              void* d_out, int out_size, void* d_ws, size_t ws_size,
                              hipStream_t stream) {
    const float* za = (const float*)d_in[0];
    const float* zb = (const float*)d_in[1];
    const int* labels = (const int*)d_in[2];
    float* out = (float*)d_out;
    float* ws = (float*)d_ws;
    int* wsi = (int*)d_ws;

    hipMemsetAsync(d_ws, 0, WS_ZERO_FLOATS * sizeof(float), stream);
    k_hist<<<128, 256, 0, stream>>>(labels, wsi + WS_COUNTS);
    k_scan<<<1, 64, 0, stream>>>(wsi + WS_COUNTS, wsi + WS_CURSOR);
    k_scatter<<<128, 256, 0, stream>>>(labels, wsi + WS_CURSOR, wsi + WS_PERM);
    k_stats<<<dim3(256, 2), 256, 0, stream>>>(za, zb, labels, ws);
    k_gram<<<dim3(16, C, 2), 256, 0, stream>>>(za, zb, wsi + WS_PERM,
                                               wsi + WS_COUNTS, ws);
    k_final<<<1, 256, 0, stream>>>(ws, out);
}

// Round 2
// 441.405 us; speedup vs baseline: 1.7627x; 1.7627x over previous
//
#include <hip/hip_runtime.h>
#include <math.h>

#define N_ROWS 32768
#define D 256
#define C 16

// workspace layout in floats
#define WS_SUMS_A 0
#define WS_SQ_A   4096
#define WS_SUMS_B 8192
#define WS_SQ_B   12288
#define WS_INV    16384
#define WS_COV    16385
#define WS_COUNTS 16392   /* int[16] */
#define WS_CURSOR 16408   /* int[16] */
#define WS_PERM   16640   /* int[32768] */
#define WS_ZERO_FLOATS 16408

typedef __attribute__((ext_vector_type(8))) __bf16 bf16x8;
typedef __attribute__((ext_vector_type(16))) float f32x16;

__device__ inline unsigned bf16_rne(float f) {
    unsigned u = __float_as_uint(f);
    return (u + 0x7fffu + ((u >> 16) & 1u)) >> 16;
}
__device__ inline unsigned pack_bf16(float lo, float hi) {
    return bf16_rne(lo) | (bf16_rne(hi) << 16);
}

__global__ __launch_bounds__(256) void k_hist(const int* __restrict__ labels,
                                              int* __restrict__ counts) {
    __shared__ int h[C];
    const int t = threadIdx.x;
    if (t < C) h[t] = 0;
    __syncthreads();
    const int i = blockIdx.x * 256 + t;
    atomicAdd(&h[labels[i]], 1);
    __syncthreads();
    if (t < C) atomicAdd(&counts[t], h[t]);
}

__global__ void k_scan(const int* __restrict__ counts, int* __restrict__ cursor) {
    if (threadIdx.x == 0) {
        int off = 0;
        for (int c = 0; c < C; ++c) { cursor[c] = off; off += counts[c]; }
    }
}

__global__ __launch_bounds__(256) void k_scatter(const int* __restrict__ labels,
                                                 int* __restrict__ cursor,
                                                 int* __restrict__ perm) {
    __shared__ int lh[C];
    __shared__ int lbase[C];
    const int t = threadIdx.x;
    if (t < C) lh[t] = 0;
    __syncthreads();
    const int i = blockIdx.x * 256 + t;
    const int lab = labels[i];
    const int lr = atomicAdd(&lh[lab], 1);
    __syncthreads();
    if (t < C) lbase[t] = atomicAdd(&cursor[t], lh[t]);
    __syncthreads();
    perm[lbase[lab] + lr] = i;
}

// Fused single-pass stats: per-class sum/sumsq for BOTH inputs + inv_loss.
// Thread t owns column t; LDS bank = t%32 -> 2-way aliasing (free).
__global__ __launch_bounds__(256) void k_stats(const float* __restrict__ za,
                                               const float* __restrict__ zb,
                                               const int* __restrict__ labels,
                                               float* __restrict__ ws) {
    const int t = threadIdx.x;
    __shared__ float S[4][C * D];   // 64 KB: sumA, sqA, sumB, sqB
    __shared__ int lab[512];
    for (int i = t; i < 4 * C * D; i += 256) ((float*)S)[i] = 0.f;
    const int r0 = blockIdx.x * 512;
    for (int i = t; i < 512; i += 256) lab[i] = labels[r0 + i];
    __syncthreads();
    float invp = 0.f;
    #pragma unroll 4
    for (int rr = 0; rr < 512; ++rr) {
        const int l = lab[rr];
        const float a = za[(size_t)(r0 + rr) * D + t];
        const float b = zb[(size_t)(r0 + rr) * D + t];
        const float dd = a - b;
        invp += dd * dd;
        S[0][l * D + t] += a;
        S[1][l * D + t] += a * a;
        S[2][l * D + t] += b;
        S[3][l * D + t] += b * b;
    }
    __syncthreads();
    #pragma unroll
    for (int c = 0; c < C; ++c) {
        atomicAdd(&ws[WS_SUMS_A + c * D + t], S[0][c * D + t]);
        atomicAdd(&ws[WS_SQ_A   + c * D + t], S[1][c * D + t]);
        atomicAdd(&ws[WS_SUMS_B + c * D + t], S[2][c * D + t]);
        atomicAdd(&ws[WS_SQ_B   + c * D + t], S[3][c * D + t]);
    }
    for (int o = 32; o > 0; o >>= 1) invp += __shfl_down(invp, o, 64);
    if ((t & 63) == 0) atomicAdd(&ws[WS_INV], invp);
}

// MFMA Gram: per (tile in {(0,0),(0,1),(1,1)}, class, input), compute the
// 128x128 Gram tile G = X_c^T X_c via bf16 32x32x16 MFMA, then
// cov = (G - n m m^T)/(n-1); accumulate weighted off-diagonal cov^2.
// LDS image is [col][k] (column-major): the Gram's A-frag and B-frag lane
// layouts coincide, so one image serves both operands.
#define STR 20   /* dwords per column: 16 data (32 bf16 k's) + 4 pad */
#define KB 32    /* k rows staged per step */

__global__ __launch_bounds__(256) void k_gram(const float* __restrict__ za,
                                              const float* __restrict__ zb,
                                              const int* __restrict__ perm,
                                              const int* __restrict__ counts,
                                              float* __restrict__ ws) {
    const int t = threadIdx.x;
    const int tile = blockIdx.x;              // 0,1,2 -> (0,0),(0,1),(1,1)
    const int tx = tile >> 1, ty = (tile + 1) >> 1;
    const int cls = blockIdx.y;
    const int inp = blockIdx.z;
    const float* X = inp ? zb : za;
    const float* sums = ws + (inp ? WS_SUMS_B : WS_SUMS_A) + cls * D;

    int offs = 0;
    for (int c = 0; c < cls; ++c) offs += counts[c];
    const int cnt = counts[cls];
    const int cm0 = tx * 128, cn0 = ty * 128;

    __shared__ __align__(16) unsigned lds[2][256 * STR];   // 2 x 20 KB

    // staging coords: p = row-pair group (0..7), cq = col quad (0..31)
    const int p  = t >> 5;
    const int cq = t & 31;
    // compute coords
    const int lane = t & 63;
    const int w = t >> 6;
    const int wr = w & 1, wc = w >> 1;        // wave's 64x64 quadrant
    const int cg = lane & 31, q = lane >> 5;

    f32x16 acc[2][2];
    #pragma unroll
    for (int i = 0; i < 2; ++i)
        #pragma unroll
        for (int j = 0; j < 2; ++j) acc[i][j] = 0.0f;

    const int nsteps = (cnt + KB - 1) / KB;

    auto stage = [&](int buf, int k0) {
        #pragma unroll
        for (int ch = 0; ch < 2; ++ch) {
            const int gc = (ch ? cn0 : cm0) + 4 * cq;
            #pragma unroll
            for (int sub = 0; sub < 2; ++sub) {
                const int rr = sub * 16 + 2 * p;          // even, 0..30
                const int r0 = k0 + rr, r1 = r0 + 1;
                float4 v0 = make_float4(0.f, 0.f, 0.f, 0.f), v1 = v0;
                if (r0 < cnt) v0 = *(const float4*)(X + (size_t)perm[offs + r0] * D + gc);
                if (r1 < cnt) v1 = *(const float4*)(X + (size_t)perm[offs + r1] * D + gc);
                unsigned* dst = &lds[buf][(ch * 128 + 4 * cq) * STR + (rr >> 1)];
                dst[0 * STR] = pack_bf16(v0.x, v1.x);
                dst[1 * STR] = pack_bf16(v0.y, v1.y);
                dst[2 * STR] = pack_bf16(v0.z, v1.z);
                dst[3 * STR] = pack_bf16(v0.w, v1.w);
            }
        }
    };

    auto frag = [&](int buf, int colbase, int h) -> bf16x8 {
        return *(const bf16x8*)&lds[buf][(colbase + cg) * STR + h * 8 + q * 4];
    };

    stage(0, 0);
    for (int s = 0; s < nsteps; ++s) {
        __syncthreads();
        const int buf = s & 1;
        if (s + 1 < nsteps) stage(buf ^ 1, (s + 1) * KB);
        #pragma unroll
        for (int h = 0; h < 2; ++h) {
            bf16x8 a0 = frag(buf, wr * 64,       h);
            bf16x8 a1 = frag(buf, wr * 64 + 32,  h);
            bf16x8 b0 = frag(buf, 128 + wc * 64,      h);
            bf16x8 b1 = frag(buf, 128 + wc * 64 + 32, h);
            acc[0][0] = __builtin_amdgcn_mfma_f32_32x32x16_bf16(a0, b0, acc[0][0], 0, 0, 0);
            acc[0][1] = __builtin_amdgcn_mfma_f32_32x32x16_bf16(a0, b1, acc[0][1], 0, 0, 0);
            acc[1][0] = __builtin_amdgcn_mfma_f32_32x32x16_bf16(a1, b0, acc[1][0], 0, 0, 0);
            acc[1][1] = __builtin_amdgcn_mfma_f32_32x32x16_bf16(a1, b1, acc[1][1], 0, 0, 0);
        }
    }

    // epilogue: cov^2 off-diagonal, weight 2 for off-diag tile
    const float fc = (float)cnt;
    const float cinv = 1.f / fc, uinv = 1.f / (fc - 1.f);
    const float wgt = (tx == ty) ? 1.f : 2.f;
    float local = 0.f;
    #pragma unroll
    for (int i = 0; i < 2; ++i) {
        #pragma unroll
        for (int j = 0; j < 2; ++j) {
            const int gn = cn0 + wc * 64 + j * 32 + (lane & 31);
            const float mn = sums[gn] * cinv;
            #pragma unroll
            for (int r = 0; r < 16; ++r) {
                const int row = (r & 3) + 8 * (r >> 2) + 4 * q;
                const int gm = cm0 + wr * 64 + i * 32 + row;
                const float cov = (acc[i][j][r] - fc * (sums[gm] * cinv) * mn) * uinv;
                if (gm != gn) local += wgt * cov * cov;
            }
        }
    }
    for (int o = 32; o > 0; o >>= 1) local += __shfl_down(local, o, 64);
    if (lane == 0) atomicAdd(&ws[WS_COV], local);
}

__global__ __launch_bounds__(256) void k_final(const float* __restrict__ ws,
                                               float* __restrict__ out) {
    __shared__ float M[C * D];    // midpoint means, 16 KB
    __shared__ float redv[4];
    __shared__ float redp[4];
    const int t = threadIdx.x;
    const int* counts = (const int*)ws + WS_COUNTS;

    float vsum = 0.f;
    for (int idx = t; idx < 2 * C * D; idx += 256) {
        const int inp = idx >> 12;
        const int cd = idx & 4095;
        const int c = cd >> 8;
        const float cnt = (float)counts[c];
        const float s  = ws[(inp ? WS_SUMS_B : WS_SUMS_A) + cd];
        const float sq = ws[(inp ? WS_SQ_B   : WS_SQ_A)   + cd];
        const float mean = s / cnt;
        const float var = (sq - cnt * mean * mean) / (cnt - 1.f);
        vsum += fmaxf(1.f - sqrtf(var + 1e-4f), 0.f);
    }
    for (int cd = t; cd < C * D; cd += 256) {
        const int c = cd >> 8;
        const float cnt = (float)counts[c];
        M[cd] = 0.5f * (ws[WS_SUMS_A + cd] + ws[WS_SUMS_B + cd]) / cnt;
    }
    for (int o = 32; o > 0; o >>= 1) vsum += __shfl_down(vsum, o, 64);
    if ((t & 63) == 0) redv[t >> 6] = vsum;
    __syncthreads();

    const int wv = t >> 6, ln = t & 63;
    float psum = 0.f;
    int p = 0;
    for (int i = 0; i < C; ++i) {
        for (int j = i + 1; j < C; ++j, ++p) {
            if ((p & 3) != wv) continue;
            float d2 = 0.f;
            #pragma unroll
            for (int d = ln; d < D; d += 64) {
                const float df = M[i * D + d] - M[j * D + d];
                d2 += df * df;
            }
            for (int o = 32; o > 0; o >>= 1) d2 += __shfl_down(d2, o, 64);
            if (ln == 0) {
                const float dist = sqrtf(d2);
                const float r = fmaxf(50.f - dist, 0.f);
                psum += r * r;
            }
        }
    }
    if (ln == 0) redp[wv] = psum;
    __syncthreads();

    if (t == 0) {
        const float var_total = redv[0] + redv[1] + redv[2] + redv[3];
        const float var_loss = var_total / 8192.f;
        const float class_sum = redp[0] + redp[1] + redp[2] + redp[3];
        const float class_loss = class_sum / 120.f;
        const float inv_loss = ws[WS_INV] / (float)(N_ROWS * D);
        const float cov_loss = 0.5f * ws[WS_COV] / (float)(C * D);
        out[0] = 25.f * inv_loss + 25.f * var_loss + 1.f * cov_loss + 50.f * class_loss;
    }
}

extern "C" void kernel_launch(void* const* d_in, const int* in_sizes, int n_in,
                              void* d_out, int out_size, void* d_ws, size_t ws_size,
                              hipStream_t stream) {
    const float* za = (const float*)d_in[0];
    const float* zb = (const float*)d_in[1];
    const int* labels = (const int*)d_in[2];
    float* out = (float*)d_out;
    float* ws = (float*)d_ws;
    int* wsi = (int*)d_ws;

    hipMemsetAsync(d_ws, 0, WS_ZERO_FLOATS * sizeof(float), stream);
    k_hist<<<128, 256, 0, stream>>>(labels, wsi + WS_COUNTS);
    k_scan<<<1, 64, 0, stream>>>(wsi + WS_COUNTS, wsi + WS_CURSOR);
    k_scatter<<<128, 256, 0, stream>>>(labels, wsi + WS_CURSOR, wsi + WS_PERM);
    k_stats<<<64, 256, 0, stream>>>(za, zb, labels, ws);
    k_gram<<<dim3(3, C, 2), 256, 0, stream>>>(za, zb, wsi + WS_PERM,
                                              wsi + WS_COUNTS, ws);
    k_final<<<1, 256, 0, stream>>>(ws, out);
}

// Round 3
// 235.995 us; speedup vs baseline: 3.2969x; 1.8704x over previous
//
#include <hip/hip_runtime.h>
#include <math.h>

#define N_ROWS 32768
#define D 256
#define C 16

// workspace layout in floats
#define WS_SUMS_A 0
#define WS_SQ_A   4096
#define WS_SUMS_B 8192
#define WS_SQ_B   12288
#define WS_INV    16384
#define WS_COV    16385
#define WS_COUNTS 16392   /* int[16] */
#define WS_CURSOR 16408   /* int[16] */
#define WS_POFFP  16424   /* int[17] padded-panel offsets */
#define WS_PERM   16640   /* int[32768] */
#define WS_ZERO_FLOATS 16408

#define MAXPAN   1040     /* >= sum_c ceil(cnt_c/32) (<=1039) */
#define PANEL_DW 5120     /* 256 cols * 20 dwords (16 data + 4 pad) */
#define WS_PANELS 65536   /* float offset of panel region */
#define WS_FAST_BYTES ((size_t)(WS_PANELS + 2 * MAXPAN * PANEL_DW) * 4)

typedef __attribute__((ext_vector_type(8))) __bf16 bf16x8;
typedef __attribute__((ext_vector_type(16))) float f32x16;

__device__ inline unsigned bf16_rne(float f) {
    unsigned u = __float_as_uint(f);
    return (u + 0x7fffu + ((u >> 16) & 1u)) >> 16;
}
__device__ inline unsigned pack_bf16(float lo, float hi) {
    return bf16_rne(lo) | (bf16_rne(hi) << 16);
}

__global__ __launch_bounds__(256) void k_hist(const int* __restrict__ labels,
                                              int* __restrict__ counts) {
    __shared__ int h[C];
    const int t = threadIdx.x;
    if (t < C) h[t] = 0;
    __syncthreads();
    const int i = blockIdx.x * 256 + t;
    atomicAdd(&h[labels[i]], 1);
    __syncthreads();
    if (t < C) atomicAdd(&counts[t], h[t]);
}

__global__ void k_scan(const int* __restrict__ counts, int* __restrict__ cursor,
                       int* __restrict__ poffp) {
    if (threadIdx.x == 0) {
        int off = 0, po = 0;
        for (int c = 0; c < C; ++c) {
            cursor[c] = off;
            poffp[c] = po;
            off += counts[c];
            po += (counts[c] + 31) >> 5;
        }
        poffp[C] = po;
    }
}

__global__ __launch_bounds__(256) void k_scatter(const int* __restrict__ labels,
                                                 int* __restrict__ cursor,
                                                 int* __restrict__ perm) {
    __shared__ int lh[C];
    __shared__ int lbase[C];
    const int t = threadIdx.x;
    if (t < C) lh[t] = 0;
    __syncthreads();
    const int i = blockIdx.x * 256 + t;
    const int lab = labels[i];
    const int lr = atomicAdd(&lh[lab], 1);
    __syncthreads();
    if (t < C) lbase[t] = atomicAdd(&cursor[t], lh[t]);
    __syncthreads();
    perm[lbase[lab] + lr] = i;
}

// One block per (class, 32-row kstep) panel. Gathers 32 rows of BOTH inputs,
// computes per-class column sums/sq + inv_loss partials, and writes the panel
// in the exact MFMA LDS image layout (col-major, STR=20, bf16 row-pairs) so
// k_gram_fast can DMA it straight into LDS.
__global__ __launch_bounds__(256) void k_pack(const float* __restrict__ za,
                                              const float* __restrict__ zb,
                                              const int* __restrict__ perm,
                                              const int* __restrict__ counts,
                                              const int* __restrict__ poffp,
                                              float* __restrict__ ws) {
    const int t = threadIdx.x;
    const int blk = blockIdx.x;
    __shared__ int sh[4];
    __shared__ __align__(16) float T[32][261];   // +5 pad: write bank 2-way (free)
    if (t == 0) {
        int c = 0;
        while (c < C && poffp[c + 1] <= blk) ++c;
        int eoff = 0;
        for (int i = 0; i < c && i < C; ++i) eoff += counts[i];
        sh[0] = c;
        sh[1] = (c < C) ? (blk - poffp[c]) : 0;
        sh[2] = eoff;
        sh[3] = (c < C) ? counts[c] : 0;
    }
    __syncthreads();
    const int cls = sh[0];
    if (cls >= C) return;
    const int kstep = sh[1], eoff = sh[2], cnt = sh[3];

    const int r = t >> 3, c8 = t & 7;            // 32 rows x 8 col-chunks
    const int lrow = kstep * 32 + r;
    const int src = (lrow < cnt) ? perm[eoff + lrow] : -1;

    float4 av[8];
    float invp = 0.f;
    unsigned* panels = (unsigned*)(ws + WS_PANELS);

    for (int ph = 0; ph < 2; ++ph) {
        const float* X = ph ? zb : za;
        float4 v[8];
        #pragma unroll
        for (int j = 0; j < 8; ++j) {
            if (src >= 0) v[j] = *(const float4*)(X + (size_t)src * D + (c8 + 8 * j) * 4);
            else v[j] = make_float4(0.f, 0.f, 0.f, 0.f);
        }
        if (ph == 0) {
            #pragma unroll
            for (int j = 0; j < 8; ++j) av[j] = v[j];
        } else {
            #pragma unroll
            for (int j = 0; j < 8; ++j) {
                const float dx = av[j].x - v[j].x, dy = av[j].y - v[j].y;
                const float dz = av[j].z - v[j].z, dw = av[j].w - v[j].w;
                invp += dx * dx + dy * dy + dz * dz + dw * dw;
            }
        }
        __syncthreads();   // prior phase's column-pass readers are done
        #pragma unroll
        for (int j = 0; j < 8; ++j)
            *(float4*)&T[r][4 * (c8 + 8 * j)] = v[j];
        __syncthreads();

        // column pass: thread t owns column t
        float s1 = 0.f, s2 = 0.f;
        unsigned pw[16];
        #pragma unroll
        for (int w = 0; w < 16; ++w) {
            const float x0 = T[2 * w][t], x1 = T[2 * w + 1][t];
            s1 += x0 + x1;
            s2 += x0 * x0 + x1 * x1;
            pw[w] = pack_bf16(x0, x1);
        }
        atomicAdd(&ws[(ph ? WS_SUMS_B : WS_SUMS_A) + cls * D + t], s1);
        atomicAdd(&ws[(ph ? WS_SQ_B   : WS_SQ_A)   + cls * D + t], s2);
        unsigned* pan = panels + ((size_t)ph * MAXPAN + blk) * PANEL_DW + t * 20;
        *(uint4*)(pan + 0)  = make_uint4(pw[0],  pw[1],  pw[2],  pw[3]);
        *(uint4*)(pan + 4)  = make_uint4(pw[4],  pw[5],  pw[6],  pw[7]);
        *(uint4*)(pan + 8)  = make_uint4(pw[8],  pw[9],  pw[10], pw[11]);
        *(uint4*)(pan + 12) = make_uint4(pw[12], pw[13], pw[14], pw[15]);
    }
    for (int o = 32; o > 0; o >>= 1) invp += __shfl_down(invp, o, 64);
    if ((t & 63) == 0) atomicAdd(&ws[WS_INV], invp);
}

// MFMA Gram over pre-packed panels: staging = global_load_lds DMA only.
__global__ __launch_bounds__(256) void k_gram_fast(const int* __restrict__ counts,
                                                   const int* __restrict__ poffp,
                                                   float* __restrict__ ws) {
    const int t = threadIdx.x;
    const int tile = blockIdx.x;              // 0,1,2 -> (0,0),(0,1),(1,1)
    const int tx = tile >> 1, ty = (tile + 1) >> 1;
    const int cls = blockIdx.y, inp = blockIdx.z;
    const int cnt = counts[cls];
    const int p0 = poffp[cls];
    const int nsteps = poffp[cls + 1] - p0;
    if (nsteps == 0) return;
    const float* sums = ws + (inp ? WS_SUMS_B : WS_SUMS_A) + cls * D;
    const unsigned* panels = (const unsigned*)(ws + WS_PANELS)
                           + (size_t)(inp * MAXPAN + p0) * PANEL_DW;
    const int cm0 = tx * 128, cn0 = ty * 128;
    const bool diag = (tx == ty);

    __shared__ __align__(16) unsigned lds[2][2][2560];   // 40 KB

    const int lane = t & 63, w = t >> 6;
    const int wr = w & 1, wc = w >> 1;
    const int cg = lane & 31, q = lane >> 5;

    f32x16 acc[2][2];
    #pragma unroll
    for (int i = 0; i < 2; ++i)
        #pragma unroll
        for (int j = 0; j < 2; ++j) acc[i][j] = 0.0f;

    auto stage = [&](int buf, int s) {
        const unsigned* base = panels + (size_t)s * PANEL_DW;
        {
            const unsigned* srcp = base + cm0 * 20;
            for (int u = t; u < 640; u += 256)
                __builtin_amdgcn_global_load_lds(
                    (const __attribute__((address_space(1))) unsigned*)(srcp + u * 4),
                    (__attribute__((address_space(3))) unsigned*)(&lds[buf][0][u * 4]),
                    16, 0, 0);
        }
        if (!diag) {
            const unsigned* srcp = base + cn0 * 20;
            for (int u = t; u < 640; u += 256)
                __builtin_amdgcn_global_load_lds(
                    (const __attribute__((address_space(1))) unsigned*)(srcp + u * 4),
                    (__attribute__((address_space(3))) unsigned*)(&lds[buf][1][u * 4]),
                    16, 0, 0);
        }
    };

    const int bch = diag ? 0 : 1;
    stage(0, 0);
    __syncthreads();
    for (int s = 0; s < nsteps; ++s) {
        const int buf = s & 1;
        if (s + 1 < nsteps) stage(buf ^ 1, s + 1);   // DMA overlaps compute below
        #pragma unroll
        for (int h = 0; h < 2; ++h) {
            bf16x8 a0 = *(const bf16x8*)&lds[buf][0][(wr * 64 + cg) * 20 + h * 8 + q * 4];
            bf16x8 a1 = *(const bf16x8*)&lds[buf][0][(wr * 64 + 32 + cg) * 20 + h * 8 + q * 4];
            bf16x8 b0 = *(const bf16x8*)&lds[buf][bch][(wc * 64 + cg) * 20 + h * 8 + q * 4];
            bf16x8 b1 = *(const bf16x8*)&lds[buf][bch][(wc * 64 + 32 + cg) * 20 + h * 8 + q * 4];
            acc[0][0] = __builtin_amdgcn_mfma_f32_32x32x16_bf16(a0, b0, acc[0][0], 0, 0, 0);
            acc[0][1] = __builtin_amdgcn_mfma_f32_32x32x16_bf16(a0, b1, acc[0][1], 0, 0, 0);
            acc[1][0] = __builtin_amdgcn_mfma_f32_32x32x16_bf16(a1, b0, acc[1][0], 0, 0, 0);
            acc[1][1] = __builtin_amdgcn_mfma_f32_32x32x16_bf16(a1, b1, acc[1][1], 0, 0, 0);
        }
        __syncthreads();
    }

    const float fc = (float)cnt;
    const float cinv = 1.f / fc, uinv = 1.f / (fc - 1.f);
    const float wgt = diag ? 1.f : 2.f;
    float local = 0.f;
    #pragma unroll
    for (int i = 0; i < 2; ++i) {
        #pragma unroll
        for (int j = 0; j < 2; ++j) {
            const int gn = cn0 + wc * 64 + j * 32 + (lane & 31);
            const float mn = sums[gn] * cinv;
            #pragma unroll
            for (int r = 0; r < 16; ++r) {
                const int row = (r & 3) + 8 * (r >> 2) + 4 * q;
                const int gm = cm0 + wr * 64 + i * 32 + row;
                const float cov = (acc[i][j][r] - fc * (sums[gm] * cinv) * mn) * uinv;
                if (gm != gn) local += wgt * cov * cov;
            }
        }
    }
    for (int o = 32; o > 0; o >>= 1) local += __shfl_down(local, o, 64);
    if (lane == 0) atomicAdd(&ws[WS_COV], local);
}

// ---------------- fallback (small ws) path: round-2 kernels ----------------
__global__ __launch_bounds__(256) void k_stats(const float* __restrict__ za,
                                               const float* __restrict__ zb,
                                               const int* __restrict__ labels,
                                               float* __restrict__ ws) {
    const int t = threadIdx.x;
    __shared__ float S[4][C * D];
    __shared__ int lab[512];
    for (int i = t; i < 4 * C * D; i += 256) ((float*)S)[i] = 0.f;
    const int r0 = blockIdx.x * 512;
    for (int i = t; i < 512; i += 256) lab[i] = labels[r0 + i];
    __syncthreads();
    float invp = 0.f;
    #pragma unroll 4
    for (int rr = 0; rr < 512; ++rr) {
        const int l = lab[rr];
        const float a = za[(size_t)(r0 + rr) * D + t];
        const float b = zb[(size_t)(r0 + rr) * D + t];
        const float dd = a - b;
        invp += dd * dd;
        S[0][l * D + t] += a;
        S[1][l * D + t] += a * a;
        S[2][l * D + t] += b;
        S[3][l * D + t] += b * b;
    }
    __syncthreads();
    #pragma unroll
    for (int c = 0; c < C; ++c) {
        atomicAdd(&ws[WS_SUMS_A + c * D + t], S[0][c * D + t]);
        atomicAdd(&ws[WS_SQ_A   + c * D + t], S[1][c * D + t]);
        atomicAdd(&ws[WS_SUMS_B + c * D + t], S[2][c * D + t]);
        atomicAdd(&ws[WS_SQ_B   + c * D + t], S[3][c * D + t]);
    }
    for (int o = 32; o > 0; o >>= 1) invp += __shfl_down(invp, o, 64);
    if ((t & 63) == 0) atomicAdd(&ws[WS_INV], invp);
}

#define STR 20
#define KB 32
__global__ __launch_bounds__(256) void k_gram_slow(const float* __restrict__ za,
                                                   const float* __restrict__ zb,
                                                   const int* __restrict__ perm,
                                                   const int* __restrict__ counts,
                                                   float* __restrict__ ws) {
    const int t = threadIdx.x;
    const int tile = blockIdx.x;
    const int tx = tile >> 1, ty = (tile + 1) >> 1;
    const int cls = blockIdx.y;
    const int inp = blockIdx.z;
    const float* X = inp ? zb : za;
    const float* sums = ws + (inp ? WS_SUMS_B : WS_SUMS_A) + cls * D;
    int offs = 0;
    for (int c = 0; c < cls; ++c) offs += counts[c];
    const int cnt = counts[cls];
    const int cm0 = tx * 128, cn0 = ty * 128;
    __shared__ __align__(16) unsigned lds[2][256 * STR];
    const int p = t >> 5, cq = t & 31;
    const int lane = t & 63, w = t >> 6;
    const int wr = w & 1, wc = w >> 1;
    const int cg = lane & 31, q = lane >> 5;
    f32x16 acc[2][2];
    #pragma unroll
    for (int i = 0; i < 2; ++i)
        #pragma unroll
        for (int j = 0; j < 2; ++j) acc[i][j] = 0.0f;
    const int nsteps = (cnt + KB - 1) / KB;
    auto stage = [&](int buf, int k0) {
        #pragma unroll
        for (int ch = 0; ch < 2; ++ch) {
            const int gc = (ch ? cn0 : cm0) + 4 * cq;
            #pragma unroll
            for (int sub = 0; sub < 2; ++sub) {
                const int rr = sub * 16 + 2 * p;
                const int r0 = k0 + rr, r1 = r0 + 1;
                float4 v0 = make_float4(0.f, 0.f, 0.f, 0.f), v1 = v0;
                if (r0 < cnt) v0 = *(const float4*)(X + (size_t)perm[offs + r0] * D + gc);
                if (r1 < cnt) v1 = *(const float4*)(X + (size_t)perm[offs + r1] * D + gc);
                unsigned* dst = &lds[buf][(ch * 128 + 4 * cq) * STR + (rr >> 1)];
                dst[0 * STR] = pack_bf16(v0.x, v1.x);
                dst[1 * STR] = pack_bf16(v0.y, v1.y);
                dst[2 * STR] = pack_bf16(v0.z, v1.z);
                dst[3 * STR] = pack_bf16(v0.w, v1.w);
            }
        }
    };
    auto frag = [&](int buf, int colbase, int h) -> bf16x8 {
        return *(const bf16x8*)&lds[buf][(colbase + cg) * STR + h * 8 + q * 4];
    };
    stage(0, 0);
    for (int s = 0; s < nsteps; ++s) {
        __syncthreads();
        const int buf = s & 1;
        if (s + 1 < nsteps) stage(buf ^ 1, (s + 1) * KB);
        #pragma unroll
        for (int h = 0; h < 2; ++h) {
            bf16x8 a0 = frag(buf, wr * 64, h);
            bf16x8 a1 = frag(buf, wr * 64 + 32, h);
            bf16x8 b0 = frag(buf, 128 + wc * 64, h);
            bf16x8 b1 = frag(buf, 128 + wc * 64 + 32, h);
            acc[0][0] = __builtin_amdgcn_mfma_f32_32x32x16_bf16(a0, b0, acc[0][0], 0, 0, 0);
            acc[0][1] = __builtin_amdgcn_mfma_f32_32x32x16_bf16(a0, b1, acc[0][1], 0, 0, 0);
            acc[1][0] = __builtin_amdgcn_mfma_f32_32x32x16_bf16(a1, b0, acc[1][0], 0, 0, 0);
            acc[1][1] = __builtin_amdgcn_mfma_f32_32x32x16_bf16(a1, b1, acc[1][1], 0, 0, 0);
        }
    }
    const float fc = (float)cnt;
    const float cinv = 1.f / fc, uinv = 1.f / (fc - 1.f);
    const float wgt = (tx == ty) ? 1.f : 2.f;
    float local = 0.f;
    #pragma unroll
    for (int i = 0; i < 2; ++i) {
        #pragma unroll
        for (int j = 0; j < 2; ++j) {
            const int gn = cn0 + wc * 64 + j * 32 + (lane & 31);
            const float mn = sums[gn] * cinv;
            #pragma unroll
            for (int r = 0; r < 16; ++r) {
                const int row = (r & 3) + 8 * (r >> 2) + 4 * q;
                const int gm = cm0 + wr * 64 + i * 32 + row;
                const float cov = (acc[i][j][r] - fc * (sums[gm] * cinv) * mn) * uinv;
                if (gm != gn) local += wgt * cov * cov;
            }
        }
    }
    for (int o = 32; o > 0; o >>= 1) local += __shfl_down(local, o, 64);
    if (lane == 0) atomicAdd(&ws[WS_COV], local);
}

__global__ __launch_bounds__(256) void k_final(const float* __restrict__ ws,
                                               float* __restrict__ out) {
    __shared__ float M[C * D];
    __shared__ float redv[4];
    __shared__ float redp[4];
    const int t = threadIdx.x;
    const int* counts = (const int*)ws + WS_COUNTS;

    float vsum = 0.f;
    for (int idx = t; idx < 2 * C * D; idx += 256) {
        const int inp = idx >> 12;
        const int cd = idx & 4095;
        const int c = cd >> 8;
        const float cnt = (float)counts[c];
        const float s  = ws[(inp ? WS_SUMS_B : WS_SUMS_A) + cd];
        const float sq = ws[(inp ? WS_SQ_B   : WS_SQ_A)   + cd];
        const float mean = s / cnt;
        const float var = (sq - cnt * mean * mean) / (cnt - 1.f);
        vsum += fmaxf(1.f - sqrtf(var + 1e-4f), 0.f);
    }
    for (int cd = t; cd < C * D; cd += 256) {
        const int c = cd >> 8;
        const float cnt = (float)counts[c];
        M[cd] = 0.5f * (ws[WS_SUMS_A + cd] + ws[WS_SUMS_B + cd]) / cnt;
    }
    for (int o = 32; o > 0; o >>= 1) vsum += __shfl_down(vsum, o, 64);
    if ((t & 63) == 0) redv[t >> 6] = vsum;
    __syncthreads();

    const int wv = t >> 6, ln = t & 63;
    float psum = 0.f;
    int p = 0;
    for (int i = 0; i < C; ++i) {
        for (int j = i + 1; j < C; ++j, ++p) {
            if ((p & 3) != wv) continue;
            float d2 = 0.f;
            #pragma unroll
            for (int d = ln; d < D; d += 64) {
                const float df = M[i * D + d] - M[j * D + d];
                d2 += df * df;
            }
            for (int o = 32; o > 0; o >>= 1) d2 += __shfl_down(d2, o, 64);
            if (ln == 0) {
                const float dist = sqrtf(d2);
                const float r = fmaxf(50.f - dist, 0.f);
                psum += r * r;
            }
        }
    }
    if (ln == 0) redp[wv] = psum;
    __syncthreads();

    if (t == 0) {
        const float var_total = redv[0] + redv[1] + redv[2] + redv[3];
        const float var_loss = var_total / 8192.f;
        const float class_sum = redp[0] + redp[1] + redp[2] + redp[3];
        const float class_loss = class_sum / 120.f;
        const float inv_loss = ws[WS_INV] / (float)(N_ROWS * D);
        const float cov_loss = 0.5f * ws[WS_COV] / (float)(C * D);
        out[0] = 25.f * inv_loss + 25.f * var_loss + 1.f * cov_loss + 50.f * class_loss;
    }
}

extern "C" void kernel_launch(void* const* d_in, const int* in_sizes, int n_in,
                              void* d_out, int out_size, void* d_ws, size_t ws_size,
                              hipStream_t stream) {
    const float* za = (const float*)d_in[0];
    const float* zb = (const float*)d_in[1];
    const int* labels = (const int*)d_in[2];
    float* out = (float*)d_out;
    float* ws = (float*)d_ws;
    int* wsi = (int*)d_ws;

    hipMemsetAsync(d_ws, 0, WS_ZERO_FLOATS * sizeof(float), stream);
    k_hist<<<128, 256, 0, stream>>>(labels, wsi + WS_COUNTS);
    k_scan<<<1, 64, 0, stream>>>(wsi + WS_COUNTS, wsi + WS_CURSOR, wsi + WS_POFFP);
    k_scatter<<<128, 256, 0, stream>>>(labels, wsi + WS_CURSOR, wsi + WS_PERM);

    if (ws_size >= WS_FAST_BYTES) {
        k_pack<<<MAXPAN, 256, 0, stream>>>(za, zb, wsi + WS_PERM,
                                           wsi + WS_COUNTS, wsi + WS_POFFP, ws);
        k_gram_fast<<<dim3(3, C, 2), 256, 0, stream>>>(wsi + WS_COUNTS,
                                                       wsi + WS_POFFP, ws);
    } else {
        k_stats<<<64, 256, 0, stream>>>(za, zb, labels, ws);
        k_gram_slow<<<dim3(3, C, 2), 256, 0, stream>>>(za, zb, wsi + WS_PERM,
                                                       wsi + WS_COUNTS, ws);
    }
    k_final<<<1, 256, 0, stream>>>(ws, out);
}